// Round 6
// baseline (674.119 us; speedup 1.0000x reference)
//
#include <hip/hip_runtime.h>

typedef _Float16 f16;
typedef _Float16 f16x8 __attribute__((ext_vector_type(8)));
typedef _Float16 f16x4 __attribute__((ext_vector_type(4)));
typedef float f32x4 __attribute__((ext_vector_type(4)));

#define MFMA16(a, b, c) __builtin_amdgcn_mfma_f32_16x16x32_f16((a), (b), (c), 0, 0, 0)
#define CLAMP01(x) __builtin_amdgcn_fmed3f((x), 0.0f, 1.0f)

constexpr int BATCH = 16384;
constexpr int H     = 256;
constexpr int IN    = 784;
constexpr int OUT   = 10;
constexpr int TSTEP = 50;
constexpr int BM    = 16;    // batch rows per block
constexpr int NTHR  = 1024;  // 16 waves = 8 slab-pairs; pair p owns h in [32p,32p+32)
constexpr int SROW  = 264;   // padded f16 row stride (33 quads -> conflict-free b128)
constexpr int S0ROW = 40;    // padded f16 row stride for s0 tile (K padded 10->32)
constexpr int DROW  = 808;   // data staging stride (101 quads, odd -> conflict-free)

// f16-unit LDS pool offsets
constexpr int OFF_S1_0 = 0;
constexpr int OFF_S1_1 = OFF_S1_0 + BM * SROW;   // 4224
constexpr int OFF_S2_0 = OFF_S1_1 + BM * SROW;   // 8448
constexpr int OFF_S2_1 = OFF_S2_0 + BM * SROW;   // 12672
constexpr int OFF_S0_0 = OFF_S2_1 + BM * SROW;   // 16896
constexpr int OFF_S0_1 = OFF_S0_0 + BM * S0ROW;  // 17536
constexpr int OFF_W0N  = OFF_S0_1 + BM * S0ROW;  // 18176  W0 natural [16][SROW]
constexpr int OFF_W0T  = OFF_W0N + 16 * SROW;    // 22400  W0^T [256][32] (o padded 10->32 w/ 0)
constexpr int POOL_F16 = OFF_W0T + 256 * 32;     // 30592 f16 = 61184 B
// Staging overlay [16][808]=12928 f16 occupies [0,12928) (state bufs, dead during prologue).
// Epilogue f32 transpose [16][264]=4224 f32 = 8448 f16 units, also overlays dead state bufs.

// Role-split design: 16 waves of ~120 VGPRs -> 4 waves/SIMD (2x R3's occupancy).
// (1024,4) caps at 128 VGPR/wave; per-wave needs ~120 so no spill (watch FETCH_SIZE).
__global__ __launch_bounds__(NTHR, 4) void ep_step_kernel(
    const float* __restrict__ data, const float* __restrict__ s0_in,
    const float* __restrict__ s1_in, const float* __restrict__ s2_in,
    const float* __restrict__ W0, const float* __restrict__ b0,
    const float* __restrict__ W2, const float* __restrict__ b2,
    const float* __restrict__ W4, const float* __restrict__ b4,
    float* __restrict__ out)
{
    __shared__ __align__(16) f16 pool[POOL_F16];

    const int tid  = threadIdx.x;
    const int wave = tid >> 6;
    const int lane = tid & 63;
    const int q    = lane >> 4;    // quad 0..3
    const int l16  = lane & 15;
    const int m0   = blockIdx.x * BM;
    const int p    = wave >> 1;    // slab-pair id 0..7
    const int role = wave & 1;     // 0: o1-wave (updates s1), 1: o2-wave (updates s2)
    const int h0   = p * 32;
    const bool doS0 = (role == 1 && p == 0);  // the bs1-reading wave of slab 0 also does s0

    // ---- phase 1: stage rho(data)->f16 (overlay), W0 natural + W0^T tiles, zero s0 bufs ------
    for (int i = tid; i < BM * (DROW / 4); i += NTHR) {
        int m  = i / (DROW / 4);
        int k4 = (i % (DROW / 4)) * 4;
        f16x4 v4 = {(f16)0.f, (f16)0.f, (f16)0.f, (f16)0.f};
        if (k4 < IN) {
            f32x4 v = *(const f32x4*)(data + (size_t)(m0 + m) * IN + k4);
            #pragma unroll
            for (int j = 0; j < 4; ++j) v4[j] = (f16)CLAMP01(v[j]);
        }
        *(f16x4*)&pool[m * DROW + k4] = v4;
    }
    for (int i = tid; i < 16 * SROW; i += NTHR) {
        int o = i / SROW, k = i % SROW;
        pool[OFF_W0N + i] = (o < OUT && k < H) ? (f16)W0[o * H + k] : (f16)0.f;
    }
    for (int i = tid; i < 256 * 32; i += NTHR) {  // W0T[h][o] = W0[o][h], o padded to 32
        int h = i >> 5, o = i & 31;
        pool[OFF_W0T + i] = (o < OUT) ? (f16)W0[o * H + h] : (f16)0.f;
    }
    for (int i = tid; i < 2 * BM * S0ROW; i += NTHR) pool[OFF_S0_0 + i] = (f16)0.f;
    __syncthreads();

    // ---- phase 2: role-dependent persistent weight fragments ----------------------------------
    // role 0: wfrag = wB, A'[h][k] = W2[h][k]  (o1 = s2 @ W2^T, transposed-C)
    // role 1: wfrag = wA, A'[h][k] = W2[k][h]  (o2 = s1 @ W2, transposed-C)
    f16x8 wfrag[2][8];
    if (role == 0) {
        #pragma unroll
        for (int ht = 0; ht < 2; ++ht) {
            int h = h0 + ht * 16 + l16;
            #pragma unroll
            for (int kk = 0; kk < 8; ++kk) {
                int kb = kk * 32 + q * 8;
                f32x4 u0 = *(const f32x4*)(W2 + h * H + kb);
                f32x4 u1 = *(const f32x4*)(W2 + h * H + kb + 4);
                f16x8 wb;
                #pragma unroll
                for (int j = 0; j < 4; ++j) { wb[j] = (f16)u0[j]; wb[j + 4] = (f16)u1[j]; }
                wfrag[ht][kk] = wb;
            }
        }
    } else {
        #pragma unroll
        for (int ht = 0; ht < 2; ++ht) {
            int h = h0 + ht * 16 + l16;
            #pragma unroll
            for (int kk = 0; kk < 8; ++kk) {
                int kb = kk * 32 + q * 8;
                f16x8 wa;
                #pragma unroll
                for (int j = 0; j < 8; ++j) wa[j] = (f16)W2[(kb + j) * H + h];
                wfrag[ht][kk] = wa;
            }
        }
    }

    // bh: role 0 -> 0.5*b2 ; role 1 -> 0.5*(x2 + b4) where x2 = rho(data) @ W4^T (slab tile)
    f32x4 bh[2];
    if (role == 1) {
        f32x4 x2a[2] = {{0.f, 0.f, 0.f, 0.f}, {0.f, 0.f, 0.f, 0.f}};
        for (int kk = 0; kk < 25; ++kk) {
            int kb = kk * 32 + q * 8;
            f16x8 bd = *(const f16x8*)&pool[l16 * DROW + kb];
            #pragma unroll
            for (int ht = 0; ht < 2; ++ht) {
                int h = h0 + ht * 16 + l16;
                f16x8 wa4;
                if (kk < 24) {
                    f32x4 u0 = *(const f32x4*)(W4 + (size_t)h * IN + kb);
                    f32x4 u1 = *(const f32x4*)(W4 + (size_t)h * IN + kb + 4);
                    #pragma unroll
                    for (int j = 0; j < 4; ++j) { wa4[j] = (f16)u0[j]; wa4[j + 4] = (f16)u1[j]; }
                } else {
                    #pragma unroll
                    for (int j = 0; j < 8; ++j) {
                        int k = kb + j;
                        wa4[j] = (k < IN) ? (f16)W4[(size_t)h * IN + k] : (f16)0.f;
                    }
                }
                x2a[ht] = MFMA16(wa4, bd, x2a[ht]);
            }
        }
        #pragma unroll
        for (int ht = 0; ht < 2; ++ht)
            #pragma unroll
            for (int r = 0; r < 4; ++r)
                bh[ht][r] = 0.5f * (x2a[ht][r] + b4[h0 + ht * 16 + q * 4 + r]);
    } else {
        #pragma unroll
        for (int ht = 0; ht < 2; ++ht)
            #pragma unroll
            for (int r = 0; r < 4; ++r)
                bh[ht][r] = 0.5f * b2[h0 + ht * 16 + q * 4 + r];
    }
    __syncthreads();  // staging overlay dead beyond this point

    // ---- master state (fp32, C layout: row h=q*4+r, col m=l16) --------------------------------
    f32x4 sm[2];  // role 0: s1 slab; role 1: s2 slab
    {
        const float* sin_ = role ? s2_in : s1_in;
        #pragma unroll
        for (int ht = 0; ht < 2; ++ht)
            #pragma unroll
            for (int r = 0; r < 4; ++r)
                sm[ht][r] = sin_[(size_t)(m0 + l16) * H + h0 + ht * 16 + q * 4 + r];
    }
    f32x4 s0m = {0.f, 0.f, 0.f, 0.f}, b0h = {0.f, 0.f, 0.f, 0.f};
    if (doS0) {
        #pragma unroll
        for (int r = 0; r < 4; ++r) {
            int o = q * 4 + r;
            if (o < OUT) { s0m[r] = s0_in[(size_t)(m0 + l16) * OUT + o]; b0h[r] = 0.5f * b0[o]; }
        }
    }

    const int s1o[2] = {OFF_S1_0, OFF_S1_1};
    const int s2o[2] = {OFF_S2_0, OFF_S2_1};
    const int s0o[2] = {OFF_S0_0, OFF_S0_1};

    auto write_state = [&](int buf) {  // wave writes the tile it OWNS (conflict-free b64)
        f16* ws = &pool[role ? s2o[buf] : s1o[buf]];
        #pragma unroll
        for (int ht = 0; ht < 2; ++ht) {
            f16x4 pk;
            #pragma unroll
            for (int r = 0; r < 4; ++r) pk[r] = (f16)sm[ht][r];
            *(f16x4*)&ws[l16 * SROW + h0 + ht * 16 + q * 4] = pk;
        }
        if (doS0) {
            int ob = q * 4;
            if (ob < OUT) {
                f16x4 pk;
                #pragma unroll
                for (int r = 0; r < 4; ++r) pk[r] = (ob + r < OUT) ? (f16)s0m[r] : (f16)0.f;
                *(f16x4*)&pool[s0o[buf] + l16 * S0ROW + ob] = pk;
            }
        }
    };

    // One step. role 0 reads s2(+s0) tiles, computes o1, updates s1.
    //           role 1 reads s1 tile, computes o2 (+ p0: o0), updates s2 (+ s0).
    // Math is bit-identical to the verified R3 kernel per output element.
    auto do_step = [&](int rb) {
        const int wb = rb ^ 1;
        const f16* rs = &pool[role ? s1o[rb] : s2o[rb]];
        f32x4 o[2] = {{0.f,0.f,0.f,0.f},{0.f,0.f,0.f,0.f}};
        f32x4 o0   = {0.f,0.f,0.f,0.f};
        #pragma unroll
        for (int kk = 0; kk < 8; ++kk) {
            int kb = kk * 32 + q * 8;
            f16x8 bs = *(const f16x8*)&rs[l16 * SROW + kb];
            o[0] = MFMA16(wfrag[0][kk], bs, o[0]);
            o[1] = MFMA16(wfrag[1][kk], bs, o[1]);
            if (doS0) {
                f16x8 a0 = *(const f16x8*)&pool[OFF_W0N + l16 * SROW + kb];
                o0 = MFMA16(a0, bs, o0);
            }
        }
        if (role == 0) {  // + s0 @ W0 contribution (K padded to 32; W0T rows zero-padded o>=10)
            f16x8 bs0 = *(const f16x8*)&pool[s0o[rb] + l16 * S0ROW + q * 8];
            f16x8 wt0 = *(const f16x8*)&pool[OFF_W0T + (h0 + l16) * 32 + q * 8];
            f16x8 wt1 = *(const f16x8*)&pool[OFF_W0T + (h0 + 16 + l16) * 32 + q * 8];
            o[0] = MFMA16(wt0, bs0, o[0]);
            o[1] = MFMA16(wt1, bs0, o[1]);
        }
        #pragma unroll
        for (int ht = 0; ht < 2; ++ht)
            #pragma unroll
            for (int r = 0; r < 4; ++r)
                sm[ht][r] = CLAMP01(fmaf(0.5f, sm[ht][r], fmaf(0.5f, o[ht][r], bh[ht][r])));
        if (doS0) {
            #pragma unroll
            for (int r = 0; r < 4; ++r)
                s0m[r] = CLAMP01(fmaf(0.5f, s0m[r], fmaf(0.5f, o0[r], b0h[r])));
        }
        write_state(wb);
    };

    write_state(0);
    __syncthreads();

    #pragma unroll 1
    for (int t = 0; t < TSTEP; t += 2) {
        do_step(0);
        __syncthreads();
        do_step(1);
        __syncthreads();
    }

    // ---- epilogue: s0 direct; s1/s2 via LDS transpose (overlay on dead state bufs) ------------
    if (doS0) {
        #pragma unroll
        for (int r = 0; r < 4; ++r) {
            int o = q * 4 + r;
            if (o < OUT) out[(size_t)(m0 + l16) * OUT + o] = s0m[r];
        }
    }
    float* xf = (float*)pool;  // [16][264] f32
    float* o1p = out + (size_t)BATCH * OUT;
    float* o2p = o1p + (size_t)BATCH * H;
    if (role == 0) {
        #pragma unroll
        for (int ht = 0; ht < 2; ++ht)
            *(f32x4*)&xf[l16 * 264 + h0 + ht * 16 + q * 4] = sm[ht];
    }
    __syncthreads();
    for (int i = tid; i < BM * H / 4; i += NTHR) {
        int m = i >> 6, c = (i & 63) * 4;
        f32x4 v = *(const f32x4*)&xf[m * 264 + c];
        *(f32x4*)&o1p[(size_t)(m0 + m) * H + c] = v;
    }
    __syncthreads();
    if (role == 1) {
        #pragma unroll
        for (int ht = 0; ht < 2; ++ht)
            *(f32x4*)&xf[l16 * 264 + h0 + ht * 16 + q * 4] = sm[ht];
    }
    __syncthreads();
    for (int i = tid; i < BM * H / 4; i += NTHR) {
        int m = i >> 6, c = (i & 63) * 4;
        f32x4 v = *(const f32x4*)&xf[m * 264 + c];
        *(f32x4*)&o2p[(size_t)(m0 + m) * H + c] = v;
    }
}

extern "C" void kernel_launch(void* const* d_in, const int* in_sizes, int n_in,
                              void* d_out, int out_size, void* d_ws, size_t ws_size,
                              hipStream_t stream) {
    const float* data  = (const float*)d_in[0];
    const float* s0_in = (const float*)d_in[1];
    const float* s1_in = (const float*)d_in[2];
    const float* s2_in = (const float*)d_in[3];
    const float* W0    = (const float*)d_in[4];
    const float* b0    = (const float*)d_in[5];
    const float* W2    = (const float*)d_in[6];
    const float* b2    = (const float*)d_in[7];
    const float* W4    = (const float*)d_in[8];
    const float* b4    = (const float*)d_in[9];
    float* out = (float*)d_out;

    ep_step_kernel<<<BATCH / BM, NTHR, 0, stream>>>(
        data, s0_in, s1_in, s2_in, W0, b0, W2, b2, W4, b4, out);
}

// Round 7
// 607.694 us; speedup vs baseline: 1.1093x; 1.1093x over previous
//
#include <hip/hip_runtime.h>

typedef _Float16 f16;
typedef _Float16 f16x8 __attribute__((ext_vector_type(8)));
typedef _Float16 f16x4 __attribute__((ext_vector_type(4)));
typedef float f32x4 __attribute__((ext_vector_type(4)));

#define MFMA16(a, b, c) __builtin_amdgcn_mfma_f32_16x16x32_f16((a), (b), (c), 0, 0, 0)
#define CLAMP01(x) __builtin_amdgcn_fmed3f((x), 0.0f, 1.0f)

constexpr int BATCH = 16384;
constexpr int H     = 256;
constexpr int IN    = 784;
constexpr int OUT   = 10;
constexpr int TSTEP = 50;
constexpr int BM    = 32;    // 2 m-tiles of 16 -> 2 independent step-chains per wave (ILP)
constexpr int NTHR  = 512;   // 8 waves; wave w owns h in [32w, 32w+32)
constexpr int SROW  = 264;   // padded f16 row stride (33 quads -> conflict-free b128)
constexpr int S0ROW = 40;    // padded f16 row stride for s0 tile (K padded 10->32)
constexpr int DROW  = 808;   // data staging stride (101 quads, odd -> conflict-free)

// Single-buffered states (compute-all / barrier / write-all / barrier per step).
constexpr int OFF_S1  = 0;                      // [32][264] = 8448
constexpr int OFF_S2  = OFF_S1 + BM * SROW;     // 8448
constexpr int OFF_S0  = OFF_S2 + BM * SROW;     // 16896  [32][40] = 1280
constexpr int OFF_W0N = OFF_S0 + BM * S0ROW;    // 18176  W0 natural [16][SROW]
constexpr int POOL_F16 = OFF_W0N + 16 * SROW;   // 22400 f16 = 44800 B
// Prologue staging overlay [16][808]=12928 f16 in [0,12928) (s1/s2 region, dead then).
// Epilogue f32 transpose [32][264] f32 = 16896 f16 units in [0,16896) (dead then).

// min-waves arg MUST stay 2 -> 256 unified VGPR+AGPR per wave (R2 lesson: 4 spills weights).
__global__ __launch_bounds__(NTHR, 2) void ep_step_kernel(
    const float* __restrict__ data, const float* __restrict__ s0_in,
    const float* __restrict__ s1_in, const float* __restrict__ s2_in,
    const float* __restrict__ W0, const float* __restrict__ b0,
    const float* __restrict__ W2, const float* __restrict__ b2,
    const float* __restrict__ W4, const float* __restrict__ b4,
    float* __restrict__ out)
{
    __shared__ __align__(16) f16 pool[POOL_F16];

    const int tid  = threadIdx.x;
    const int wave = tid >> 6;
    const int lane = tid & 63;
    const int q    = lane >> 4;   // quad 0..3
    const int l16  = lane & 15;
    const int m0   = blockIdx.x * BM;
    const int h0   = wave * 32;   // this wave's 32-column h slab (2 tiles of 16)

    // ---- phase 1a: W0-natural tile + zero s0 buf (disjoint from staging overlay) -------------
    for (int i = tid; i < 16 * SROW; i += NTHR) {
        int o = i / SROW, k = i % SROW;
        pool[OFF_W0N + i] = (o < OUT && k < H) ? (f16)W0[o * H + k] : (f16)0.f;
    }
    for (int i = tid; i < BM * S0ROW; i += NTHR) pool[OFF_S0 + i] = (f16)0.f;

    // ---- phase 1b: persistent register weight fragments (R3 verbatim) -------------------------
    f16x8 wB[2][8];  // A'[h][k] = W2[h][k]   (for out1 = s2 @ W2^T)
    f16x8 wA[2][8];  // A'[h][k] = W2[k][h]   (for out2 = s1 @ W2)
    #pragma unroll
    for (int ht = 0; ht < 2; ++ht) {
        int h = h0 + ht * 16 + l16;
        #pragma unroll
        for (int kk = 0; kk < 8; ++kk) {
            int kb = kk * 32 + q * 8;
            f32x4 u0 = *(const f32x4*)(W2 + h * H + kb);
            f32x4 u1 = *(const f32x4*)(W2 + h * H + kb + 4);
            f16x8 wb;
            #pragma unroll
            for (int j = 0; j < 4; ++j) { wb[j] = (f16)u0[j]; wb[j + 4] = (f16)u1[j]; }
            wB[ht][kk] = wb;
            f16x8 wa;
            #pragma unroll
            for (int j = 0; j < 8; ++j) wa[j] = (f16)W2[(kb + j) * H + h];
            wA[ht][kk] = wa;
        }
    }
    f16x8 w0c[2];  // A'[h][o] = W0[o][h], K padded 10->32 (registers, as R3)
    #pragma unroll
    for (int ht = 0; ht < 2; ++ht) {
        int h = h0 + ht * 16 + l16;
        #pragma unroll
        for (int j = 0; j < 8; ++j) {
            int o = q * 8 + j;
            w0c[ht][j] = (o < OUT) ? (f16)W0[o * H + h] : (f16)0.f;
        }
    }

    // ---- phase 2: per-tile staging + x2 GEMM (R3 loop verbatim, run twice) --------------------
    f32x4 x2h[2][2], b2h[2];
    #pragma unroll 1
    for (int mt = 0; mt < 2; ++mt) {
        __syncthreads();  // staging buffer free (prev readers done / phase-1a writers done)
        for (int i = tid; i < 16 * (DROW / 4); i += NTHR) {
            int m  = i / (DROW / 4);
            int k4 = (i % (DROW / 4)) * 4;
            f16x4 p = {(f16)0.f, (f16)0.f, (f16)0.f, (f16)0.f};
            if (k4 < IN) {
                f32x4 v = *(const f32x4*)(data + (size_t)(m0 + mt * 16 + m) * IN + k4);
                #pragma unroll
                for (int j = 0; j < 4; ++j) p[j] = (f16)CLAMP01(v[j]);
            }
            *(f16x4*)&pool[m * DROW + k4] = p;
        }
        __syncthreads();
        f32x4 x2a[2] = {{0.f, 0.f, 0.f, 0.f}, {0.f, 0.f, 0.f, 0.f}};
        for (int kk = 0; kk < 25; ++kk) {
            int kb = kk * 32 + q * 8;
            f16x8 bd = *(const f16x8*)&pool[l16 * DROW + kb];
            #pragma unroll
            for (int ht = 0; ht < 2; ++ht) {
                int h = h0 + ht * 16 + l16;
                f16x8 wa4;
                if (kk < 24) {
                    f32x4 u0 = *(const f32x4*)(W4 + (size_t)h * IN + kb);
                    f32x4 u1 = *(const f32x4*)(W4 + (size_t)h * IN + kb + 4);
                    #pragma unroll
                    for (int j = 0; j < 4; ++j) { wa4[j] = (f16)u0[j]; wa4[j + 4] = (f16)u1[j]; }
                } else {
                    #pragma unroll
                    for (int j = 0; j < 8; ++j) {
                        int k = kb + j;
                        wa4[j] = (k < IN) ? (f16)W4[(size_t)h * IN + k] : (f16)0.f;
                    }
                }
                x2a[ht] = MFMA16(wa4, bd, x2a[ht]);
            }
        }
        #pragma unroll
        for (int ht = 0; ht < 2; ++ht)
            #pragma unroll
            for (int r = 0; r < 4; ++r)
                x2h[mt][ht][r] = 0.5f * (x2a[ht][r] + b4[h0 + ht * 16 + q * 4 + r]);
    }
    #pragma unroll
    for (int ht = 0; ht < 2; ++ht)
        #pragma unroll
        for (int r = 0; r < 4; ++r)
            b2h[ht][r] = 0.5f * b2[h0 + ht * 16 + q * 4 + r];
    __syncthreads();  // staging overlay dead beyond this point

    // ---- fp32 master states (C layout: row h=q*4+r, col m=mt*16+l16), R3-form loads ----------
    f32x4 s1m[2][2], s2m[2][2];
    #pragma unroll
    for (int mt = 0; mt < 2; ++mt)
        #pragma unroll
        for (int ht = 0; ht < 2; ++ht)
            #pragma unroll
            for (int r = 0; r < 4; ++r) {
                size_t base = (size_t)(m0 + mt * 16 + l16) * H + h0 + ht * 16 + q * 4 + r;
                s1m[mt][ht][r] = s1_in[base];
                s2m[mt][ht][r] = s2_in[base];
            }
    f32x4 s0m[2] = {{0.f,0.f,0.f,0.f},{0.f,0.f,0.f,0.f}};
    f32x4 b0h = {0.f, 0.f, 0.f, 0.f};
    if (wave == 0) {
        #pragma unroll
        for (int mt = 0; mt < 2; ++mt)
            #pragma unroll
            for (int r = 0; r < 4; ++r) {
                int o = q * 4 + r;
                if (o < OUT) {
                    s0m[mt][r] = s0_in[(size_t)(m0 + mt * 16 + l16) * OUT + o];
                    if (mt == 0) b0h[r] = 0.5f * b0[o];
                }
            }
    }

    // conflict-free b64 writeback of tile mt into the single state buffers
    auto writeback = [&](int mt) {
        int mrow = mt * 16 + l16;
        #pragma unroll
        for (int ht = 0; ht < 2; ++ht) {
            int hb = h0 + ht * 16 + q * 4;
            f16x4 p1, p2;
            #pragma unroll
            for (int r = 0; r < 4; ++r) { p1[r] = (f16)s1m[mt][ht][r]; p2[r] = (f16)s2m[mt][ht][r]; }
            *(f16x4*)&pool[OFF_S1 + mrow * SROW + hb] = p1;
            *(f16x4*)&pool[OFF_S2 + mrow * SROW + hb] = p2;
        }
        if (wave == 0) {
            int ob = q * 4;
            if (ob < OUT) {
                f16x4 p;
                #pragma unroll
                for (int r = 0; r < 4; ++r) p[r] = (ob + r < OUT) ? (f16)s0m[mt][r] : (f16)0.f;
                *(f16x4*)&pool[OFF_S0 + mrow * S0ROW + ob] = p;
            }
        }
    };

    // compute phase for tile mt (reads only; R3's do_step front half, per-element identical)
    auto compute = [&](int mt, f32x4 o1[2], f32x4 o2[2], f32x4& o0) {
        int mrow = mt * 16 + l16;
        #pragma unroll
        for (int kk = 0; kk < 8; ++kk) {
            int kb = kk * 32 + q * 8;
            f16x8 bs1 = *(const f16x8*)&pool[OFF_S1 + mrow * SROW + kb];
            f16x8 bs2 = *(const f16x8*)&pool[OFF_S2 + mrow * SROW + kb];
            o2[0] = MFMA16(wA[0][kk], bs1, o2[0]);
            o2[1] = MFMA16(wA[1][kk], bs1, o2[1]);
            o1[0] = MFMA16(wB[0][kk], bs2, o1[0]);
            o1[1] = MFMA16(wB[1][kk], bs2, o1[1]);
            if (wave == 0) {
                f16x8 a0 = *(const f16x8*)&pool[OFF_W0N + l16 * SROW + kb];
                o0 = MFMA16(a0, bs1, o0);
            }
        }
        f16x8 bs0 = *(const f16x8*)&pool[OFF_S0 + mrow * S0ROW + q * 8];
        o1[0] = MFMA16(w0c[0], bs0, o1[0]);
        o1[1] = MFMA16(w0c[1], bs0, o1[1]);
    };

    auto update = [&](int mt, f32x4 o1[2], f32x4 o2[2], f32x4& o0) {
        #pragma unroll
        for (int ht = 0; ht < 2; ++ht)
            #pragma unroll
            for (int r = 0; r < 4; ++r) {
                s1m[mt][ht][r] = CLAMP01(fmaf(0.5f, s1m[mt][ht][r], fmaf(0.5f, o1[ht][r], b2h[ht][r])));
                s2m[mt][ht][r] = CLAMP01(fmaf(0.5f, s2m[mt][ht][r], fmaf(0.5f, o2[ht][r], x2h[mt][ht][r])));
            }
        if (wave == 0) {
            #pragma unroll
            for (int r = 0; r < 4; ++r)
                s0m[mt][r] = CLAMP01(fmaf(0.5f, s0m[mt][r], fmaf(0.5f, o0[r], b0h[r])));
        }
        writeback(mt);
    };

    writeback(0);
    writeback(1);
    __syncthreads();

    // ---- main loop: compute both tiles (2 independent chains) / barrier / update / barrier ----
    #pragma unroll 1
    for (int t = 0; t < TSTEP; ++t) {
        f32x4 o1a[2] = {{0.f,0.f,0.f,0.f},{0.f,0.f,0.f,0.f}};
        f32x4 o2a[2] = {{0.f,0.f,0.f,0.f},{0.f,0.f,0.f,0.f}};
        f32x4 o1b[2] = {{0.f,0.f,0.f,0.f},{0.f,0.f,0.f,0.f}};
        f32x4 o2b[2] = {{0.f,0.f,0.f,0.f},{0.f,0.f,0.f,0.f}};
        f32x4 o0a = {0.f,0.f,0.f,0.f}, o0b = {0.f,0.f,0.f,0.f};
        compute(0, o1a, o2a, o0a);
        compute(1, o1b, o2b, o0b);
        __syncthreads();               // all reads of old state complete
        update(0, o1a, o2a, o0a);
        update(1, o1b, o2b, o0b);
        __syncthreads();               // new state visible
    }

    // ---- epilogue: s0 direct; s1/s2 via LDS transpose (overlay on dead state bufs) ------------
    if (wave == 0) {
        #pragma unroll
        for (int mt = 0; mt < 2; ++mt)
            #pragma unroll
            for (int r = 0; r < 4; ++r) {
                int o = q * 4 + r;
                if (o < OUT) out[(size_t)(m0 + mt * 16 + l16) * OUT + o] = s0m[mt][r];
            }
    }
    float* xf = (float*)pool;  // [32][264] f32
    float* o1p = out + (size_t)BATCH * OUT;
    float* o2p = o1p + (size_t)BATCH * H;
    #pragma unroll
    for (int mt = 0; mt < 2; ++mt)
        #pragma unroll
        for (int ht = 0; ht < 2; ++ht)
            *(f32x4*)&xf[(mt * 16 + l16) * 264 + h0 + ht * 16 + q * 4] = s1m[mt][ht];
    __syncthreads();
    for (int i = tid; i < BM * H / 4; i += NTHR) {
        int m = i >> 6, c = (i & 63) * 4;
        f32x4 v = *(const f32x4*)&xf[m * 264 + c];
        *(f32x4*)&o1p[(size_t)(m0 + m) * H + c] = v;
    }
    __syncthreads();
    #pragma unroll
    for (int mt = 0; mt < 2; ++mt)
        #pragma unroll
        for (int ht = 0; ht < 2; ++ht)
            *(f32x4*)&xf[(mt * 16 + l16) * 264 + h0 + ht * 16 + q * 4] = s2m[mt][ht];
    __syncthreads();
    for (int i = tid; i < BM * H / 4; i += NTHR) {
        int m = i >> 6, c = (i & 63) * 4;
        f32x4 v = *(const f32x4*)&xf[m * 264 + c];
        *(f32x4*)&o2p[(size_t)(m0 + m) * H + c] = v;
    }
}

extern "C" void kernel_launch(void* const* d_in, const int* in_sizes, int n_in,
                              void* d_out, int out_size, void* d_ws, size_t ws_size,
                              hipStream_t stream) {
    const float* data  = (const float*)d_in[0];
    const float* s0_in = (const float*)d_in[1];
    const float* s1_in = (const float*)d_in[2];
    const float* s2_in = (const float*)d_in[3];
    const float* W0    = (const float*)d_in[4];
    const float* b0    = (const float*)d_in[5];
    const float* W2    = (const float*)d_in[6];
    const float* b2    = (const float*)d_in[7];
    const float* W4    = (const float*)d_in[8];
    const float* b4    = (const float*)d_in[9];
    float* out = (float*)d_out;

    ep_step_kernel<<<BATCH / BM, NTHR, 0, stream>>>(
        data, s0_in, s1_in, s2_in, W0, b0, W2, b2, W4, b4, out);
}